// Round 10
// baseline (512.394 us; speedup 1.0000x reference)
//
#include <hip/hip_runtime.h>
#include <math.h>

#define BB 512
#define TT 1024
#define LL 48
#define PF 8            // steps per phase = emission ring depth
#define TSTRIDE 49      // padded T row stride: bank = (17*i + j) % 32, conflict-free

__device__ __forceinline__ float readlane_f(float v, int lane) {
    return __int_as_float(__builtin_amdgcn_readlane(__float_as_int(v), lane));
}

// One DPP butterfly/broadcast stage of a full-wave max (register-file cross-lane).
template <int CTRL>
__device__ __forceinline__ float dppmax(float x) {
    int y = __builtin_amdgcn_update_dpp(__float_as_int(x), __float_as_int(x),
                                        CTRL, 0xF, 0xF, false);
    return fmaxf(x, __int_as_float(y));
}

// Wave max of z, then lowest-lane index of bitwise equality (== reference
// first-max argmax; lanes holding -INF never match). ~13 VALU + 1 SALU.
__device__ __forceinline__ int wave_argmax(float z) {
    float r = z;
    r = dppmax<0xB1>(r);    // quad_perm [1,0,3,2] : xor 1
    r = dppmax<0x4E>(r);    // quad_perm [2,3,0,1] : xor 2
    r = dppmax<0x141>(r);   // row_half_mirror     : xor 4
    r = dppmax<0x140>(r);   // row_mirror          : xor 8
    r = dppmax<0x142>(r);   // row_bcast15         : 16->31, 47->63 merge
    r = dppmax<0x143>(r);   // row_bcast31         : lane 63 = full-wave max
    float m = readlane_f(r, 63);
    unsigned long long eq = __ballot(z == m);
    return (int)__builtin_ctzll(eq);     // s_ff1: lowest index wins ties
}

// Forward stores VALUES ONLY; backtrack recomputes the one on-path argmax per
// step (bitwise-identical floats, ffs tie-break).
//
// Round-10: the step body is pure {1 ds_write_b32 -> 12 broadcast
// ds_read_b128 -> adds -> per-q4 max tree}; NO fence (memcpy reads alias the
// vbuf float store, so write->read order is already guaranteed — round 9's
// per-step asm memory fence was chopping the scheduler's window and pinning
// global-op vmcnt churn onto the serial chain), and NO global ops (v-rows
// park in vsave[8]; stores + emission refills cluster in a flush block
// between 8-step phases).
__global__ __launch_bounds__(64)
__attribute__((amdgpu_waves_per_eu(1, 1)))
void viterbi_kernel(
    const float* __restrict__ emissions,   // [B,T,L]
    const float* __restrict__ transitions, // [L,L]
    const float* __restrict__ start_tr,    // [L]
    const float* __restrict__ end_tr,      // [L]
    int* __restrict__ out,                 // [B,T] int32
    float* __restrict__ vws)               // workspace: [B][T][L] viterbi rows
{
    __shared__ float tlds[LL * TSTRIDE];   // T padded for backtrack column reads
    __shared__ __align__(16) float vbuf[64];      // v broadcast buffer (48 + slack)

    const int b  = blockIdx.x;
    const int j  = threadIdx.x;
    const int jc = (j < LL) ? j : (LL - 1);       // lanes 48-63 mirror lane 47

    // Transition column jc in registers (forward); T into LDS (backtrack).
    float tc[LL];
#pragma unroll
    for (int i = 0; i < LL; ++i) {
        tc[i] = transitions[i * LL + jc];
        tlds[i * TSTRIDE + jc] = tc[i];    // lanes 48-63 dup-write col 47: same value
    }
#pragma unroll
    for (int i = 0; i < LL; ++i)
        asm volatile("" : "+v"(tc[i]));    // pin: forbid remat-as-load (round-4 mode)

    const float* em = emissions + (size_t)b * TT * LL;
    float* vr_g = vws + (size_t)b * TT * LL;      // this chain's [T][48] rows

    float v = start_tr[jc] + em[jc];
    vr_g[jc] = v;                                  // row 0 (dup lanes: same value)

    // Emission ring: er[k] = e(tb + k) for the current phase.
    float er[PF];
#pragma unroll
    for (int k = 0; k < PF; ++k)
        er[k] = em[(size_t)(1 + k) * LL + jc];

    // One value-only Viterbi step (serial chain: v -> LDS -> v). Pure VALU+DS.
    auto step = [&](float e) {
        vbuf[j] = v;                       // 1 ds_write_b32 (lanes 48-63: slack)
        float pm[12];
#pragma unroll
        for (int r = 0; r < 12; ++r) {
            float4 q;
            __builtin_memcpy(&q, &vbuf[4 * r], 16);   // ds_read_b128, uniform addr
            float s0 = q.x + tc[4 * r + 0];
            float s1 = q.y + tc[4 * r + 1];
            float s2 = q.z + tc[4 * r + 2];
            float s3 = q.w + tc[4 * r + 3];
            pm[r] = fmaxf(fmaxf(s0, s1), fmaxf(s2, s3));   // closes per-q4
        }
        float c0 = fmaxf(fmaxf(pm[0], pm[1]), pm[2]);
        float c1 = fmaxf(fmaxf(pm[3], pm[4]), pm[5]);
        float c2 = fmaxf(fmaxf(pm[6], pm[7]), pm[8]);
        float c3 = fmaxf(fmaxf(pm[9], pm[10]), pm[11]);
        float best = fmaxf(fmaxf(c0, c1), fmaxf(c2, c3));
        v = best + e;                      // chain continues here
    };

    float vsave[PF];                       // parked v-rows of one phase

    // Main loop: phases of 8 pure steps + one vmem flush block.
    int tb = 1;
    for (; tb + PF <= TT; tb += PF) {      // tb = 1, 9, ..., 1009
#pragma unroll
        for (int k = 0; k < PF; ++k) { step(er[k]); vsave[k] = v; }
        // flush: park rows to global, refill ring with e(tb+8 .. tb+15)
#pragma unroll
        for (int k = 0; k < PF; ++k) {
            vr_g[(size_t)(tb + k) * LL + jc] = vsave[k];
            int tn = tb + PF + k; if (tn > TT - 1) tn = TT - 1;
            er[k] = em[(size_t)tn * LL + jc];
        }
    }
    // Tail: tb = 1017, steps 1017..1023 consume er[0..6] (filled last flush).
#pragma unroll
    for (int k = 0; k < PF - 1; ++k) {
        int t = tb + k;
        if (t < TT) { step(er[k]); vr_g[(size_t)t * LL + jc] = v; }
    }

    // ---- final tag: wave-parallel argmax of v + end ----
    float vf = (j < LL) ? (v + end_tr[jc]) : -INFINITY;
    int tag = wave_argmax(vf);                     // uniform (SGPR) tag

    int* ob = out + (size_t)b * TT;
    if (j == 0) ob[TT - 1] = tag;

    // ---- backtrack: recompute argmax only along the path ----
    // tag_p = argmax_i( v_p[i] + T[i][tag_{p+1}] ), p = T-2 .. 0.
    for (int hi = TT - 2; hi >= 0; hi -= 32) {
        int lo = hi - 31; if (lo < 0) lo = 0;
        int n = hi - lo + 1;                       // wave-uniform

        float vr[32];
#pragma unroll
        for (int k = 31; k >= 0; --k)              // issue order == consume order
            if (k < n) vr[k] = vr_g[(size_t)(lo + k) * LL + jc];

        int outv = 0;
#pragma unroll
        for (int k = 31; k >= 0; --k) {
            if (k < n) {
                // lane i reads T[i][tag]: dwords (17*i + tag) % 32 -> no conflicts
                float tcol = tlds[jc * TSTRIDE + tag];
                float z = (j < LL) ? (vr[k] + tcol) : -INFINITY;
                tag = wave_argmax(z);              // chain: ds_read+add+dpp+ballot
                outv = (j == k) ? tag : outv;      // tag is SGPR -> one cndmask
            }
        }
        if (j < n) ob[lo + j] = outv;
    }
}

extern "C" void kernel_launch(void* const* d_in, const int* in_sizes, int n_in,
                              void* d_out, int out_size, void* d_ws, size_t ws_size,
                              hipStream_t stream) {
    const float* emissions   = (const float*)d_in[0];
    // d_in[1] = mask — unused by the reference decode body
    const float* transitions = (const float*)d_in[2];
    const float* start_tr    = (const float*)d_in[3];
    const float* end_tr      = (const float*)d_in[4];
    int* out = (int*)d_out;

    // Viterbi rows: B * T * L * 4 = 100,663,296 B in the provided workspace.
    float* vws = (float*)d_ws;

    viterbi_kernel<<<dim3(BB), dim3(64), 0, stream>>>(
        emissions, transitions, start_tr, end_tr, out, vws);
}